// Round 24
// baseline (896.932 us; speedup 1.0000x reference)
//
#include <hip/hip_runtime.h>
#include <hip/hip_bf16.h>
#include <stdint.h>

typedef float f32x4 __attribute__((ext_vector_type(4)));
typedef float f32x16 __attribute__((ext_vector_type(16)));
typedef int i32x4 __attribute__((ext_vector_type(4)));
typedef int i32x8 __attribute__((ext_vector_type(8)));
typedef long i64;

#define BM 256
#define BN 256
#define BKB 64   // K elements (=bytes, fp8) per tile step

// 16B-chunk slot = chunk ^ swz(row); period 16 covers the 32-row frag read.
__device__ __host__ __forceinline__ int swz(int r) {
  return ((r >> 1) ^ (r >> 3)) & 3;
}

// ---------------- pre-quant: fp32 (bf16-valued) -> fp8 e4m3fn, LINEAR -------
__global__ __launch_bounds__(256) void quant_fp8_from_f32(
    const float* __restrict__ in, const float* __restrict__ scale,
    uint8_t* __restrict__ out, int n16) {
  const int i = blockIdx.x * blockDim.x + threadIdx.x;
  if (i >= n16) return;
  const float inv_s = 1.0f / scale[0];
  const float* p = in + (i64)i * 16;
  f32x4 v[4];
  v[0] = *(const f32x4*)p;
  v[1] = *(const f32x4*)(p + 4);
  v[2] = *(const f32x4*)(p + 8);
  v[3] = *(const f32x4*)(p + 12);
  uint32_t w[4];
#pragma unroll
  for (int q = 0; q < 4; q++) {
    float f0 = fminf(fmaxf(v[q][0] * inv_s, -448.f), 448.f);
    float f1 = fminf(fmaxf(v[q][1] * inv_s, -448.f), 448.f);
    float f2 = fminf(fmaxf(v[q][2] * inv_s, -448.f), 448.f);
    float f3 = fminf(fmaxf(v[q][3] * inv_s, -448.f), 448.f);
    int r = 0;
    r = __builtin_amdgcn_cvt_pk_fp8_f32(f0, f1, r, false);
    r = __builtin_amdgcn_cvt_pk_fp8_f32(f2, f3, r, true);
    w[q] = (uint32_t)r;
  }
  ((uint4*)out)[i] = make_uint4(w[0], w[1], w[2], w[3]);
}

__device__ __forceinline__ void gload_lds16(const void* g, void* l) {
  __builtin_amdgcn_global_load_lds(
      (const __attribute__((address_space(1))) uint32_t*)g,
      (__attribute__((address_space(3))) uint32_t*)l, 16, 0, 0);
}

__device__ __forceinline__ float bf16_rne_f32(float f) {
  union { float f; uint32_t u; } c; c.f = f;
  uint32_t lsb = (c.u >> 16) & 1u;
  c.u += 0x7FFFu + lsb;
  c.u &= 0xFFFF0000u;
  return c.f;
}

// ---------------- fp8 GEMM via MX-scaled 32x32x64 MFMA (scales = 1.0) -------
// 256x256 tile, 4 waves (2x2), wave-tile 128x128, acc[4][4] f32x16 (256 AGPR)
// at ONE wave per SIMD (512-reg cap, launch_bounds(256,1)). This is the only
// wave-tile whose LDS demand (16 b128 reads / 16 MFMA = 1 KB/MFMA ~= 235
// B/cyc) fits under the 256 B/cyc LDS roof -- the 2x2 (2 KB/MFMA, ceiling
// 36% = R23's measured 35%) and 4x2 (1.5 KB, ceiling 54%) tiles are
// LDS-bandwidth-bound by arithmetic. Counted-vmcnt double-buffer loop
// (R19/R23-proven): [stage next tile (8 gloads/thread); vmcnt(8); barrier;
// ds_read+MFMA (column-major, small liveness); barrier].
__global__ __launch_bounds__(256, 1) void gemm_fp8_mx(
    const uint8_t* __restrict__ Aq, const uint8_t* __restrict__ Bq,
    const float* __restrict__ bias,
    const float* __restrict__ xs, const float* __restrict__ wsc,
    float* __restrict__ C, int M, int N, int K) {
  __shared__ uint8_t sA[2][BM * BKB];   // 2 x 16 KB
  __shared__ uint8_t sB[2][BN * BKB];   // 2 x 16 KB

  const int nbn = N / BN;
  int bid = blockIdx.x;
  { int cpx = gridDim.x >> 3; bid = (bid & 7) * cpx + (bid >> 3); }  // XCD swizzle
  const int bm = bid / nbn;
  const int bn = bid % nbn;

  const int t = threadIdx.x, lane = t & 63, wave = t >> 6;
  const int wm = (wave >> 1) * 128;   // 2x2 waves, 128x128 each
  const int wn = (wave & 1) * 128;
  const int g = lane >> 5;            // K-half group
  const int r31 = lane & 31;

  f32x16 acc[4][4];
#pragma unroll
  for (int i = 0; i < 4; i++)
#pragma unroll
    for (int j = 0; j < 4; j++) acc[i][j] = (f32x16)0.f;

  // ---- staging: thread t stages chunk (t&3) of rows (t>>2)+64j, j=0..3 ----
  const int srow = t >> 2;            // 0..63
  const int c16 = t & 3;
  i64 src[4];
#pragma unroll
  for (int j = 0; j < 4; j++) {
    const int row = srow + 64 * j;
    src[j] = (i64)row * K + ((c16 ^ swz(row)) << 4);
  }
  const uint8_t* gA = Aq + (i64)(bm * BM) * K;
  const uint8_t* gB = Bq + (i64)(bn * BN) * K;

  // ---- fragment read offsets (hoisted) ----
  int aoff[4][2], boff[4][2];
#pragma unroll
  for (int i = 0; i < 4; i++) {
    const int ra = wm + i * 32 + r31;
    const int sa_ = swz(ra);
    aoff[i][0] = ra * 64 + (((2 * g + 0) ^ sa_) << 4);
    aoff[i][1] = ra * 64 + (((2 * g + 1) ^ sa_) << 4);
    const int rb = wn + i * 32 + r31;
    const int sb_ = swz(rb);
    boff[i][0] = rb * 64 + (((2 * g + 0) ^ sb_) << 4);
    boff[i][1] = rb * 64 + (((2 * g + 1) ^ sb_) << 4);
  }

  const int NT = K / BKB;
  // prologue: stage tile 0 into buffer 0 (8 loads/thread in flight)
#pragma unroll
  for (int j = 0; j < 4; j++) {
    gload_lds16(gA + src[j], &sA[0][t * 16 + j * 4096]);
    gload_lds16(gB + src[j], &sB[0][t * 16 + j * 4096]);
  }

  int cur = 0;
  for (int it = 0; it < NT; ++it) {
    if (it + 1 < NT) {
      // issue next tile's 8 loads; they stay in flight across the barrier
      const i64 kt = (i64)(it + 1) * BKB;
      const int nxt = cur ^ 1;
#pragma unroll
      for (int j = 0; j < 4; j++) {
        gload_lds16(gA + src[j] + kt, &sA[nxt][t * 16 + j * 4096]);
        gload_lds16(gB + src[j] + kt, &sB[nxt][t * 16 + j * 4096]);
      }
      asm volatile("s_waitcnt vmcnt(8)" ::: "memory");   // current tile landed
    } else {
      asm volatile("s_waitcnt vmcnt(0)" ::: "memory");   // final tile landed
    }
    __builtin_amdgcn_s_barrier();   // collective: tile `it` fully in LDS

    // column-major MFMA order: 4 B-frags persist (32 regs), one A-frag (8
    // regs) refilled per row -> small operand liveness on top of acc 256.
    union opnd { i32x4 h[2]; i32x8 v; };
    union opnd ub[4];
#pragma unroll
    for (int j = 0; j < 4; j++) {
      ub[j].h[0] = *(const i32x4*)(&sB[cur][0] + boff[j][0]);
      ub[j].h[1] = *(const i32x4*)(&sB[cur][0] + boff[j][1]);
    }
#pragma unroll
    for (int i = 0; i < 4; i++) {
      union opnd ua;
      ua.h[0] = *(const i32x4*)(&sA[cur][0] + aoff[i][0]);
      ua.h[1] = *(const i32x4*)(&sA[cur][0] + aoff[i][1]);
#pragma unroll
      for (int j = 0; j < 4; j++)
        acc[i][j] = __builtin_amdgcn_mfma_scale_f32_32x32x64_f8f6f4(
            ua.v, ub[j].v, acc[i][j],
            0, 0,          // cbsz=fp8(e4m3), blgp=fp8(e4m3)
            0, 127,        // scale_a = e8m0 1.0
            0, 127);       // scale_b = e8m0 1.0
    }

    // all waves' reads of buf[cur] are register-consumed before this barrier;
    // after it, the next iteration may overwrite the staged buffer.
    __builtin_amdgcn_s_barrier();
    cur ^= 1;
  }

  // ---- epilogue: bf16_rne(acc*(sx*sw) + bias) stored as FP32 -------------
  // 32x32 C/D layout (m74/m101): col = lane&31, row = (reg&3)+8*(reg>>2)+4*g
  const float sc = xs[0] * wsc[0];
#pragma unroll
  for (int j = 0; j < 4; j++) {
    const int col = bn * BN + wn + j * 32 + r31;
    const float bv = bias[col];
#pragma unroll
    for (int i = 0; i < 4; i++) {
      const int rowbase = bm * BM + wm + i * 32 + 4 * g;
#pragma unroll
      for (int reg = 0; reg < 16; reg++) {
        const int row = rowbase + (reg & 3) + 8 * (reg >> 2);
        C[(i64)row * N + col] = bf16_rne_f32(acc[i][j][reg] * sc + bv);
      }
    }
  }
}

extern "C" void kernel_launch(void* const* d_in, const int* in_sizes, int n_in,
                              void* d_out, int out_size, void* d_ws, size_t ws_size,
                              hipStream_t stream) {
  // Verified I/O model (R11 oracle + R12-R23 passes): declared order, element
  // counts, ALL buffers fp32-stored bf16-valued, output fp32.
  const float* x = (const float*)d_in[0];
  const float* w = (const float*)d_in[1];
  const float* bias = (const float*)d_in[2];
  const float* x_scale = (const float*)d_in[3];
  const float* w_scale = (const float*)d_in[4];

  const int N = in_sizes[2];
  const int K = in_sizes[1] / N;
  const int M = in_sizes[0] / K;

  uint8_t* xq = (uint8_t*)d_ws;                     // M*K = 32 MB
  uint8_t* wq = (uint8_t*)d_ws + (size_t)M * K;     // N*K = 64 MB

  {
    const int n16 = (M * K) / 16;
    quant_fp8_from_f32<<<(n16 + 255) / 256, 256, 0, stream>>>(x, x_scale, xq, n16);
  }
  {
    const int n16 = (int)(((i64)N * K) / 16);
    quant_fp8_from_f32<<<(n16 + 255) / 256, 256, 0, stream>>>(w, w_scale, wq, n16);
  }

  dim3 grid((M / BM) * (N / BN));
  gemm_fp8_mx<<<grid, 256, 0, stream>>>(
      xq, wq, bias, x_scale, w_scale, (float*)d_out, M, N, K);
}

// Round 25
// 723.419 us; speedup vs baseline: 1.2399x; 1.2399x over previous
//
#include <hip/hip_runtime.h>
#include <hip/hip_bf16.h>
#include <stdint.h>

typedef float f32x4 __attribute__((ext_vector_type(4)));
typedef float f32x16 __attribute__((ext_vector_type(16)));
typedef int i32x4 __attribute__((ext_vector_type(4)));
typedef int i32x8 __attribute__((ext_vector_type(8)));
typedef long i64;

#define BM 256
#define BN 128
#define BKB 64   // K elements (=bytes, fp8) per tile step

// 16B-chunk slot = chunk ^ swz(row); period 16 covers the 32-row frag read.
__device__ __host__ __forceinline__ int swz(int r) {
  return ((r >> 1) ^ (r >> 3)) & 3;
}

// ---------------- pre-quant: fp32 (bf16-valued) -> fp8 e4m3fn, LINEAR -------
__global__ __launch_bounds__(256) void quant_fp8_from_f32(
    const float* __restrict__ in, const float* __restrict__ scale,
    uint8_t* __restrict__ out, int n16) {
  const int i = blockIdx.x * blockDim.x + threadIdx.x;
  if (i >= n16) return;
  const float inv_s = 1.0f / scale[0];
  const float* p = in + (i64)i * 16;
  f32x4 v[4];
  v[0] = *(const f32x4*)p;
  v[1] = *(const f32x4*)(p + 4);
  v[2] = *(const f32x4*)(p + 8);
  v[3] = *(const f32x4*)(p + 12);
  uint32_t w[4];
#pragma unroll
  for (int q = 0; q < 4; q++) {
    float f0 = fminf(fmaxf(v[q][0] * inv_s, -448.f), 448.f);
    float f1 = fminf(fmaxf(v[q][1] * inv_s, -448.f), 448.f);
    float f2 = fminf(fmaxf(v[q][2] * inv_s, -448.f), 448.f);
    float f3 = fminf(fmaxf(v[q][3] * inv_s, -448.f), 448.f);
    int r = 0;
    r = __builtin_amdgcn_cvt_pk_fp8_f32(f0, f1, r, false);
    r = __builtin_amdgcn_cvt_pk_fp8_f32(f2, f3, r, true);
    w[q] = (uint32_t)r;
  }
  ((uint4*)out)[i] = make_uint4(w[0], w[1], w[2], w[3]);
}

__device__ __forceinline__ void gload_lds16(const void* g, void* l) {
  __builtin_amdgcn_global_load_lds(
      (const __attribute__((address_space(1))) uint32_t*)g,
      (__attribute__((address_space(3))) uint32_t*)l, 16, 0, 0);
}

__device__ __forceinline__ float bf16_rne_f32(float f) {
  union { float f; uint32_t u; } c; c.f = f;
  uint32_t lsb = (c.u >> 16) & 1u;
  c.u += 0x7FFFu + lsb;
  c.u &= 0xFFFF0000u;
  return c.f;
}

// ---------------- fp8 GEMM via MX-scaled 32x32x64 MFMA (scales = 1.0) -------
// 256x128 tile, 4 waves (2Mx2N), wave-tile 128x64 = the MFMA-bound shape
// (per block-step: MFMA 550 cyc > LDS 281 cyc), acc[4][2] f32x16 (128 AGPR,
// R19's exact per-wave state: compiled clean at VGPR 100). LDS dbuf = 48 KB
// -> TWO blocks/CU co-resident (96 KB <= 160; regs 2x228 <= 512/SIMD): one
// block's MFMA phase hides the other's read/stage latency -- the overlap the
// R19 1-block lockstep (32% util) lacked. Counted-vmcnt loop (R18 lesson:
// vmcnt counts per-THREAD instructions = 6 gloads/step here).
__global__ __launch_bounds__(256, 2) void gemm_fp8_mx(
    const uint8_t* __restrict__ Aq, const uint8_t* __restrict__ Bq,
    const float* __restrict__ bias,
    const float* __restrict__ xs, const float* __restrict__ wsc,
    float* __restrict__ C, int M, int N, int K) {
  __shared__ uint8_t sA[2][BM * BKB];   // 2 x 16 KB
  __shared__ uint8_t sB[2][BN * BKB];   // 2 x 8 KB

  const int nbn = N / BN;
  int bid = blockIdx.x;
  { int cpx = gridDim.x >> 3; bid = (bid & 7) * cpx + (bid >> 3); }  // XCD swizzle
  const int bm = bid / nbn;
  const int bn = bid % nbn;

  const int t = threadIdx.x, lane = t & 63, wave = t >> 6;
  const int wm = (wave >> 1) * 128;   // 2 wave-rows of 128
  const int wn = (wave & 1) * 64;     // 2 wave-cols of 64
  const int g = lane >> 5;            // K-half group
  const int r31 = lane & 31;

  f32x16 acc[4][2];
#pragma unroll
  for (int i = 0; i < 4; i++)
#pragma unroll
    for (int j = 0; j < 2; j++) acc[i][j] = (f32x16)0.f;

  // ---- staging: thread t stages chunk (t&3) of rows (t>>2)+64j ----
  // A: j=0..3 (256 rows), B: j=0..1 (128 rows). 6 gloads/thread/step.
  const int srow = t >> 2;            // 0..63
  const int c16 = t & 3;
  i64 src[4];
#pragma unroll
  for (int j = 0; j < 4; j++) {
    const int row = srow + 64 * j;
    src[j] = (i64)row * K + ((c16 ^ swz(row)) << 4);
  }
  const uint8_t* gA = Aq + (i64)(bm * BM) * K;
  const uint8_t* gB = Bq + (i64)(bn * BN) * K;

  // ---- fragment read offsets (hoisted) ----
  int aoff[4][2], boff[2][2];
#pragma unroll
  for (int i = 0; i < 4; i++) {
    const int ra = wm + i * 32 + r31;
    const int sa_ = swz(ra);
    aoff[i][0] = ra * 64 + (((2 * g + 0) ^ sa_) << 4);
    aoff[i][1] = ra * 64 + (((2 * g + 1) ^ sa_) << 4);
  }
#pragma unroll
  for (int j = 0; j < 2; j++) {
    const int rb = wn + j * 32 + r31;
    const int sb_ = swz(rb);
    boff[j][0] = rb * 64 + (((2 * g + 0) ^ sb_) << 4);
    boff[j][1] = rb * 64 + (((2 * g + 1) ^ sb_) << 4);
  }

  const int NT = K / BKB;
  // prologue: stage tile 0 into buffer 0 (6 loads/thread in flight)
#pragma unroll
  for (int j = 0; j < 4; j++)
    gload_lds16(gA + src[j], &sA[0][t * 16 + j * 4096]);
#pragma unroll
  for (int j = 0; j < 2; j++)
    gload_lds16(gB + src[j], &sB[0][t * 16 + j * 4096]);

  int cur = 0;
  for (int it = 0; it < NT; ++it) {
    if (it + 1 < NT) {
      // issue next tile's 6 loads; they stay in flight across the barrier
      const i64 kt = (i64)(it + 1) * BKB;
      const int nxt = cur ^ 1;
#pragma unroll
      for (int j = 0; j < 4; j++)
        gload_lds16(gA + src[j] + kt, &sA[nxt][t * 16 + j * 4096]);
#pragma unroll
      for (int j = 0; j < 2; j++)
        gload_lds16(gB + src[j] + kt, &sB[nxt][t * 16 + j * 4096]);
      asm volatile("s_waitcnt vmcnt(6)" ::: "memory");   // current tile landed
    } else {
      asm volatile("s_waitcnt vmcnt(0)" ::: "memory");   // final tile landed
    }
    __builtin_amdgcn_s_barrier();   // collective: tile `it` fully in LDS

    // column-pair order: ub0, ub1 persist (16 regs); ua (8) refilled per row.
    union opnd { i32x4 h[2]; i32x8 v; };
    union opnd ub[2];
#pragma unroll
    for (int j = 0; j < 2; j++) {
      ub[j].h[0] = *(const i32x4*)(&sB[cur][0] + boff[j][0]);
      ub[j].h[1] = *(const i32x4*)(&sB[cur][0] + boff[j][1]);
    }
#pragma unroll
    for (int i = 0; i < 4; i++) {
      union opnd ua;
      ua.h[0] = *(const i32x4*)(&sA[cur][0] + aoff[i][0]);
      ua.h[1] = *(const i32x4*)(&sA[cur][0] + aoff[i][1]);
#pragma unroll
      for (int j = 0; j < 2; j++)
        acc[i][j] = __builtin_amdgcn_mfma_scale_f32_32x32x64_f8f6f4(
            ua.v, ub[j].v, acc[i][j],
            0, 0,          // cbsz=fp8(e4m3), blgp=fp8(e4m3)
            0, 127,        // scale_a = e8m0 1.0
            0, 127);       // scale_b = e8m0 1.0
    }

    // all waves' reads of buf[cur] are register-consumed before this barrier;
    // after it, the next iteration may overwrite the staged buffer.
    __builtin_amdgcn_s_barrier();
    cur ^= 1;
  }

  // ---- epilogue: bf16_rne(acc*(sx*sw) + bias) stored as FP32 -------------
  // 32x32 C/D layout (m74/m101): col = lane&31, row = (reg&3)+8*(reg>>2)+4*g
  const float sc = xs[0] * wsc[0];
#pragma unroll
  for (int j = 0; j < 2; j++) {
    const int col = bn * BN + wn + j * 32 + r31;
    const float bv = bias[col];
#pragma unroll
    for (int i = 0; i < 4; i++) {
      const int rowbase = bm * BM + wm + i * 32 + 4 * g;
#pragma unroll
      for (int reg = 0; reg < 16; reg++) {
        const int row = rowbase + (reg & 3) + 8 * (reg >> 2);
        C[(i64)row * N + col] = bf16_rne_f32(acc[i][j][reg] * sc + bv);
      }
    }
  }
}

extern "C" void kernel_launch(void* const* d_in, const int* in_sizes, int n_in,
                              void* d_out, int out_size, void* d_ws, size_t ws_size,
                              hipStream_t stream) {
  // Verified I/O model (R11 oracle + R12-R24 passes): declared order, element
  // counts, ALL buffers fp32-stored bf16-valued, output fp32.
  const float* x = (const float*)d_in[0];
  const float* w = (const float*)d_in[1];
  const float* bias = (const float*)d_in[2];
  const float* x_scale = (const float*)d_in[3];
  const float* w_scale = (const float*)d_in[4];

  const int N = in_sizes[2];
  const int K = in_sizes[1] / N;
  const int M = in_sizes[0] / K;

  uint8_t* xq = (uint8_t*)d_ws;                     // M*K = 32 MB
  uint8_t* wq = (uint8_t*)d_ws + (size_t)M * K;     // N*K = 64 MB

  {
    const int n16 = (M * K) / 16;
    quant_fp8_from_f32<<<(n16 + 255) / 256, 256, 0, stream>>>(x, x_scale, xq, n16);
  }
  {
    const int n16 = (int)(((i64)N * K) / 16);
    quant_fp8_from_f32<<<(n16 + 255) / 256, 256, 0, stream>>>(w, w_scale, wq, n16);
  }

  dim3 grid((M / BM) * (N / BN));
  gemm_fp8_mx<<<grid, 256, 0, stream>>>(
      xq, wq, bias, x_scale, w_scale, (float*)d_out, M, N, K);
}